// Round 1
// baseline (559.380 us; speedup 1.0000x reference)
//
#include <hip/hip_runtime.h>
#include <math.h>

// Problem constants (fixed by setup_inputs)
#define B_   4
#define L_   512
#define D_   768
#define K_   10
#define P_   50
#define R_   1586          // 2*D + P
#define NP_  10642         // number of window pairs
#define MROWS 2048         // B_*L_

// out layout: pred [B,n] | emo_cau_pos [n,2] | h [B,n,R]  (all as float)
#define PRED_OFF 0
#define POS_OFF  (B_ * NP_)                 // 42568
#define H_OFF    (B_ * NP_ + NP_ * 2)       // 63852

// ---- closed-form pair indexing: pairs ordered (ei outer asc, ci inner asc) ----
__device__ __forceinline__ int pair_offset(int i) {
    // sum over t < i of window count cnt(t) = min(L-1,t+K) - max(0,t-K) + 1
    int h = i < K_ ? i : K_;
    int off = h * (K_ + 1) + (h * (h - 1)) / 2;     // head rows, cnt = t+K+1
    if (i > K_) {
        int fullEnd = i < (L_ - K_) ? i : (L_ - K_);
        off += (fullEnd - K_) * (2 * K_ + 1);        // full windows
        if (i > L_ - K_) {
            int t = i - (L_ - K_);                   // tail rows count
            int first = 2 * K_;                      // cnt at t = L-K
            int last = L_ + K_ - (i - 1);            // cnt at t = i-1
            off += (first + last) * t / 2;
        }
    }
    return off;
}

// ---- Kernel A: F[21][R] = E @ W1[1536:1586,:] + b1, E[s] = sum_r cnt_r*exp(-(s-r)^2)*pos_emb[r]
__global__ __launch_bounds__(256) void build_F(
        const float* __restrict__ pos_emb,   // [21, 50]
        const float* __restrict__ W1,        // [R, R]
        const float* __restrict__ b1,        // [R]
        float* __restrict__ F) {             // [21, R]
    int s = blockIdx.x;                      // 0..20
    __shared__ float Es[P_];
    if (threadIdx.x < P_) {
        float acc = 0.f;
        #pragma unroll
        for (int r = 0; r <= 2 * K_; ++r) {
            float cnt = (float)(L_ - (r > K_ ? r - K_ : K_ - r));
            float d = (float)(s - r);
            acc += cnt * expf(-d * d) * pos_emb[r * P_ + threadIdx.x];
        }
        Es[threadIdx.x] = acc;
    }
    __syncthreads();
    for (int j = threadIdx.x; j < R_; j += blockDim.x) {
        float acc = b1[j];
        #pragma unroll 10
        for (int p = 0; p < P_; ++p)
            acc += Es[p] * W1[(2 * D_ + p) * R_ + j];
        F[s * R_ + j] = acc;
    }
}

// ---- Kernel B: U = doc@W1[0:768,:], V = doc@W1[768:1536,:]  (fp32 tiled GEMM)
// grid: (ceil(R/64)=25, MROWS/64=32, 2), block: 256 (16x16 threads, 4x4 per thread)
__global__ __launch_bounds__(256) void gemm_uv(
        const float* __restrict__ A,     // [2048, 768]
        const float* __restrict__ W1,    // [R, R]
        float* __restrict__ U,           // [2048, R]
        float* __restrict__ V) {         // [2048, R]
    const float* Wbase = W1 + (size_t)blockIdx.z * D_ * R_;
    float* C = blockIdx.z ? V : U;
    const int tileM = blockIdx.y * 64;
    const int tileN = blockIdx.x * 64;
    __shared__ float As[16][68];   // [k][m], pad 68: 16B-aligned cols, 2-way bank alias (free)
    __shared__ float Bs[16][68];   // [k][n]
    const int tx = threadIdx.x & 15;      // col group
    const int ty = threadIdx.x >> 4;      // row group
    float acc[4][4] = {};

    for (int k0 = 0; k0 < D_; k0 += 16) {
        #pragma unroll
        for (int l = 0; l < 4; ++l) {
            int idx = threadIdx.x + l * 256;          // 0..1023
            int m  = idx >> 4, kk = idx & 15;         // A[m][kk]
            As[kk][m] = A[(size_t)(tileM + m) * D_ + k0 + kk];
            int nn = idx & 63, k2 = idx >> 6;         // B[k2][nn]
            int col = tileN + nn;
            Bs[k2][nn] = (col < R_) ? Wbase[(size_t)(k0 + k2) * R_ + col] : 0.f;
        }
        __syncthreads();
        #pragma unroll
        for (int kk = 0; kk < 16; ++kk) {
            float4 a4 = *(const float4*)&As[kk][ty * 4];
            float4 b4 = *(const float4*)&Bs[kk][tx * 4];
            const float a[4] = {a4.x, a4.y, a4.z, a4.w};
            const float b[4] = {b4.x, b4.y, b4.z, b4.w};
            #pragma unroll
            for (int i = 0; i < 4; ++i)
                #pragma unroll
                for (int j = 0; j < 4; ++j)
                    acc[i][j] += a[i] * b[j];
        }
        __syncthreads();
    }
    #pragma unroll
    for (int i = 0; i < 4; ++i) {
        int row = tileM + ty * 4 + i;
        #pragma unroll
        for (int j = 0; j < 4; ++j) {
            int col = tileN + tx * 4 + j;
            if (col < R_) C[(size_t)row * R_ + col] = acc[i][j];
        }
    }
}

// ---- Kernel C: per-pair epilogue. grid = B*L*21 blocks; invalid (i,dj) exit.
__global__ __launch_bounds__(256) void epilogue(
        const float* __restrict__ U, const float* __restrict__ V,
        const float* __restrict__ F,
        const float* __restrict__ W2, const float* __restrict__ b2,
        float* __restrict__ out) {
    int bz  = blockIdx.x;
    int b   = bz / (L_ * 21);
    int rem = bz % (L_ * 21);
    int i   = rem / 21;
    int dj  = rem % 21;
    int j   = i - K_ + dj;
    if (j < 0 || j >= L_) return;
    int base = i - K_ > 0 ? i - K_ : 0;
    int p = pair_offset(i) + (j - base);

    const float2* u2 = (const float2*)(U + (size_t)(b * L_ + i) * R_);
    const float2* v2 = (const float2*)(V + (size_t)(b * L_ + j) * R_);
    const float2* f2 = (const float2*)(F + (size_t)dj * R_);
    const float2* w2 = (const float2*)W2;
    float2* h2 = (float2*)(out + H_OFF + (size_t)(b * NP_ + p) * R_);

    float acc = 0.f;
    for (int c = threadIdx.x; c < R_ / 2; c += blockDim.x) {
        float2 uu = u2[c], vv = v2[c], ff = f2[c], ww = w2[c];
        float h0 = fmaxf(uu.x + vv.x + ff.x, 0.f);
        float h1 = fmaxf(uu.y + vv.y + ff.y, 0.f);
        h2[c] = make_float2(h0, h1);
        acc += h0 * ww.x + h1 * ww.y;
    }
    // block reduce (4 waves of 64)
    #pragma unroll
    for (int off = 32; off; off >>= 1) acc += __shfl_down(acc, off, 64);
    __shared__ float red[4];
    int lane = threadIdx.x & 63, wid = threadIdx.x >> 6;
    if (lane == 0) red[wid] = acc;
    __syncthreads();
    if (threadIdx.x == 0) {
        out[PRED_OFF + b * NP_ + p] = red[0] + red[1] + red[2] + red[3] + b2[0];
        if (b == 0) {
            out[POS_OFF + p * 2 + 0] = (float)(i + 1);
            out[POS_OFF + p * 2 + 1] = (float)(j + 1);
        }
    }
}

extern "C" void kernel_launch(void* const* d_in, const int* in_sizes, int n_in,
                              void* d_out, int out_size, void* d_ws, size_t ws_size,
                              hipStream_t stream) {
    const float* doc     = (const float*)d_in[0];  // [B, L, D]
    const float* pos_emb = (const float*)d_in[1];  // [21, 50]
    const float* W1      = (const float*)d_in[2];  // [R, R]
    const float* b1      = (const float*)d_in[3];  // [R]
    const float* W2      = (const float*)d_in[4];  // [R] (R x 1)
    const float* b2      = (const float*)d_in[5];  // [1]
    float* out = (float*)d_out;

    float* U = (float*)d_ws;                        // [2048, R]  ~13 MB
    float* V = U + (size_t)MROWS * R_;              // [2048, R]  ~13 MB
    float* F = V + (size_t)MROWS * R_;              // [21, R]    ~133 KB

    build_F<<<21, 256, 0, stream>>>(pos_emb, W1, b1, F);
    gemm_uv<<<dim3((R_ + 63) / 64, MROWS / 64, 2), 256, 0, stream>>>(doc, W1, U, V);
    epilogue<<<B_ * L_ * 21, 256, 0, stream>>>(U, V, F, W2, b2, out);
}

// Round 2
// 395.202 us; speedup vs baseline: 1.4154x; 1.4154x over previous
//
#include <hip/hip_runtime.h>
#include <math.h>

// Problem constants (fixed by setup_inputs)
#define B_   4
#define L_   512
#define D_   768
#define K_   10
#define P_   50
#define R_   1586          // 2*D + P
#define NP_  10642         // number of window pairs
#define MROWS 2048         // B_*L_
#define NPAD 1664          // 13*128, padded N for MFMA tiles

// out layout: pred [B,n] | emo_cau_pos [n,2] | h [B,n,R]  (all as float)
#define PRED_OFF 0
#define POS_OFF  (B_ * NP_)
#define H_OFF    (B_ * NP_ + NP_ * 2)

typedef __attribute__((ext_vector_type(8))) short short8;    // 8 bf16, 4 VGPRs (MFMA A/B frag)
typedef __attribute__((ext_vector_type(4))) float floatx4;   // MFMA C/D frag

__device__ __forceinline__ unsigned short f2bf(float f) {
    union { float f; unsigned int u; } a; a.f = f;
    unsigned int u = a.u;
    return (unsigned short)((u + 0x7FFF + ((u >> 16) & 1)) >> 16);  // RNE
}

// ---- closed-form pair indexing: pairs ordered (ei outer asc, ci inner asc) ----
__device__ __forceinline__ int pair_offset(int i) {
    int h = i < K_ ? i : K_;
    int off = h * (K_ + 1) + (h * (h - 1)) / 2;
    if (i > K_) {
        int fullEnd = i < (L_ - K_) ? i : (L_ - K_);
        off += (fullEnd - K_) * (2 * K_ + 1);
        if (i > L_ - K_) {
            int t = i - (L_ - K_);
            int first = 2 * K_;
            int last = L_ + K_ - (i - 1);
            off += (first + last) * t / 2;
        }
    }
    return off;
}

// ---- convert doc -> bf16 row-major [2048][768] ----
__global__ __launch_bounds__(256) void convert_A(
        const float* __restrict__ doc, unsigned short* __restrict__ At) {
    int idx = (blockIdx.x * 256 + threadIdx.x) * 4;    // total 2048*768 = 1572864
    float4 v = *(const float4*)(doc + idx);
    ushort4 o;
    o.x = f2bf(v.x); o.y = f2bf(v.y); o.z = f2bf(v.z); o.w = f2bf(v.w);
    *(ushort4*)(At + idx) = o;
}

// ---- transpose+convert W1 rows [z*768, z*768+768) -> Wt[z][n][k] bf16, n padded to 1664 ----
__global__ __launch_bounds__(256) void convert_W(
        const float* __restrict__ W1, unsigned short* __restrict__ Wt) {
    int z = blockIdx.z;
    int k0 = blockIdx.x * 32;          // k in [0,768)
    int n0 = blockIdx.y * 32;          // n in [0,1664)
    __shared__ float tile[32][33];
    int tx = threadIdx.x & 31, ty = threadIdx.x >> 5;   // 32 x 8
    #pragma unroll
    for (int r = 0; r < 4; ++r) {
        int k = k0 + ty + r * 8;
        int n = n0 + tx;
        tile[ty + r * 8][tx] = (n < R_) ? W1[(size_t)(z * D_ + k) * R_ + n] : 0.f;
    }
    __syncthreads();
    #pragma unroll
    for (int r = 0; r < 4; ++r) {
        int n = n0 + ty + r * 8;
        int k = k0 + tx;
        Wt[(size_t)z * NPAD * D_ + (size_t)n * D_ + k] = f2bf(tile[tx][ty + r * 8]);
    }
}

// ---- F[21][R] = E @ W1[1536:1586,:] + b1 (fp32, tiny) ----
__global__ __launch_bounds__(256) void build_F(
        const float* __restrict__ pos_emb, const float* __restrict__ W1,
        const float* __restrict__ b1, float* __restrict__ F) {
    int s = blockIdx.x;                      // 0..20
    __shared__ float Es[P_];
    if (threadIdx.x < P_) {
        float acc = 0.f;
        #pragma unroll
        for (int r = 0; r <= 2 * K_; ++r) {
            float cnt = (float)(L_ - (r > K_ ? r - K_ : K_ - r));
            float d = (float)(s - r);
            acc += cnt * expf(-d * d) * pos_emb[r * P_ + threadIdx.x];
        }
        Es[threadIdx.x] = acc;
    }
    __syncthreads();
    for (int j = threadIdx.x; j < R_; j += blockDim.x) {
        float acc = b1[j];
        #pragma unroll 10
        for (int p = 0; p < P_; ++p)
            acc += Es[p] * W1[(2 * D_ + p) * R_ + j];
        F[s * R_ + j] = acc;
    }
}

// ---- MFMA GEMM: C[z] = At(2048x768,bf16) @ Wt[z]^T -> fp32 [2048][1586]
// 128x128 tile, BK=32, 4 waves, each wave 64x64 = 4x4 mfma_16x16x32
#define GLOAD_LDS16(g, l) __builtin_amdgcn_global_load_lds( \
    (const __attribute__((address_space(1))) void*)(g), \
    (__attribute__((address_space(3))) void*)(l), 16, 0, 0)

__global__ __launch_bounds__(256) void gemm_mfma(
        const unsigned short* __restrict__ At,   // [2048][768] bf16
        const unsigned short* __restrict__ Wt,   // [2][1664][768] bf16 (B^T)
        float* __restrict__ U, float* __restrict__ V) {
    __shared__ unsigned short Alds[128 * 32];    // [m][k] row-major, 8 KB
    __shared__ unsigned short Blds[128 * 32];    // [n][k] row-major, 8 KB
    const int tileN = blockIdx.x * 128;
    const int tileM = blockIdx.y * 128;
    const unsigned short* Bt = Wt + (size_t)blockIdx.z * NPAD * D_;
    float* C = blockIdx.z ? V : U;

    const int lane = threadIdx.x & 63;
    const int w = threadIdx.x >> 6;
    const int wm = (w & 1) * 64, wn = (w >> 1) * 64;
    const int quad = lane >> 4, l16 = lane & 15;

    floatx4 acc[4][4] = {};

    for (int k0 = 0; k0 < D_; k0 += 32) {
        #pragma unroll
        for (int t = 0; t < 2; ++t) {
            int g = (t * 4 + w) * 64 + lane;     // 0..511
            int m = g >> 2, c = g & 3;           // row in tile, 16B chunk in 64B row
            GLOAD_LDS16(At + (size_t)(tileM + m) * D_ + k0 + c * 8,
                        Alds + (t * 4 + w) * 512);
            GLOAD_LDS16(Bt + (size_t)(tileN + m) * D_ + k0 + c * 8,
                        Blds + (t * 4 + w) * 512);
        }
        __syncthreads();   // drains vmcnt before barrier -> LDS visible
        short8 a[4], b[4];
        #pragma unroll
        for (int im = 0; im < 4; ++im)
            a[im] = *(const short8*)&Alds[(wm + im * 16 + l16) * 32 + quad * 8];
        #pragma unroll
        for (int in = 0; in < 4; ++in)
            b[in] = *(const short8*)&Blds[(wn + in * 16 + l16) * 32 + quad * 8];
        #pragma unroll
        for (int im = 0; im < 4; ++im)
            #pragma unroll
            for (int in = 0; in < 4; ++in)
                acc[im][in] = __builtin_amdgcn_mfma_f32_16x16x32_bf16(
                    a[im], b[in], acc[im][in], 0, 0, 0);
        __syncthreads();
    }
    #pragma unroll
    for (int im = 0; im < 4; ++im) {
        #pragma unroll
        for (int in = 0; in < 4; ++in) {
            int col = tileN + wn + in * 16 + l16;
            if (col < R_) {
                #pragma unroll
                for (int r = 0; r < 4; ++r) {
                    int row = tileM + wm + im * 16 + quad * 4 + r;
                    C[(size_t)row * R_ + col] = acc[im][in][r];
                }
            }
        }
    }
}

// ---- epilogue: one WAVE per (b, i, dj); h = relu(U_row + V_row + F_row); pred = h . W2 + b2
__global__ __launch_bounds__(256) void epilogue(
        const float* __restrict__ U, const float* __restrict__ V,
        const float* __restrict__ F, const float* __restrict__ W2,
        const float* __restrict__ b2, float* __restrict__ out) {
    int Wid = blockIdx.x * 4 + (threadIdx.x >> 6);    // 0 .. 4*512*21-1
    int lane = threadIdx.x & 63;
    int b   = Wid / (L_ * 21);
    int rem = Wid % (L_ * 21);
    int i   = rem / 21;
    int dj  = rem % 21;
    int j   = i - K_ + dj;
    if (j < 0 || j >= L_) return;
    int base = i - K_ > 0 ? i - K_ : 0;
    int p = pair_offset(i) + (j - base);

    const float2* u2 = (const float2*)(U + (size_t)(b * L_ + i) * R_);
    const float2* v2 = (const float2*)(V + (size_t)(b * L_ + j) * R_);
    const float2* f2 = (const float2*)(F + (size_t)dj * R_);
    const float2* w2 = (const float2*)W2;
    float2* h2 = (float2*)(out + H_OFF + (size_t)(b * NP_ + p) * R_);

    float acc = 0.f;
    #pragma unroll 4
    for (int c = lane; c < R_ / 2; c += 64) {   // R/2 = 793 float2s
        float2 uu = u2[c], vv = v2[c], ff = f2[c], ww = w2[c];
        float h0 = fmaxf(uu.x + vv.x + ff.x, 0.f);
        float h1 = fmaxf(uu.y + vv.y + ff.y, 0.f);
        h2[c] = make_float2(h0, h1);
        acc += h0 * ww.x + h1 * ww.y;
    }
    #pragma unroll
    for (int off = 32; off; off >>= 1) acc += __shfl_down(acc, off, 64);
    if (lane == 0) {
        out[PRED_OFF + b * NP_ + p] = acc + b2[0];
        if (b == 0) {
            out[POS_OFF + p * 2 + 0] = (float)(i + 1);
            out[POS_OFF + p * 2 + 1] = (float)(j + 1);
        }
    }
}

extern "C" void kernel_launch(void* const* d_in, const int* in_sizes, int n_in,
                              void* d_out, int out_size, void* d_ws, size_t ws_size,
                              hipStream_t stream) {
    const float* doc     = (const float*)d_in[0];
    const float* pos_emb = (const float*)d_in[1];
    const float* W1      = (const float*)d_in[2];
    const float* b1      = (const float*)d_in[3];
    const float* W2      = (const float*)d_in[4];
    const float* b2      = (const float*)d_in[5];
    float* out = (float*)d_out;

    char* ws = (char*)d_ws;
    float* U = (float*)ws;                               // 2048*1586 f32
    float* V = U + (size_t)MROWS * R_;                   // 2048*1586 f32
    float* F = V + (size_t)MROWS * R_;                   // 21*1586 f32
    size_t off = ((size_t)MROWS * R_ * 2 + (size_t)21 * R_) * 4;
    off = (off + 255) & ~(size_t)255;
    unsigned short* At = (unsigned short*)(ws + off);    // 2048*768 bf16
    off += (size_t)MROWS * D_ * 2;
    off = (off + 255) & ~(size_t)255;
    unsigned short* Wt = (unsigned short*)(ws + off);    // 2*1664*768 bf16

    convert_A<<<MROWS * D_ / 1024, 256, 0, stream>>>(doc, At);
    convert_W<<<dim3(D_ / 32, NPAD / 32, 2), 256, 0, stream>>>(W1, Wt);
    build_F<<<21, 256, 0, stream>>>(pos_emb, W1, b1, F);
    gemm_mfma<<<dim3(NPAD / 128, MROWS / 128, 2), 256, 0, stream>>>(At, Wt, U, V);
    epilogue<<<B_ * L_ * 21 / 4, 256, 0, stream>>>(U, V, F, W2, b2, out);
}

// Round 3
// 371.985 us; speedup vs baseline: 1.5038x; 1.0624x over previous
//
#include <hip/hip_runtime.h>
#include <math.h>

// Problem constants (fixed by setup_inputs)
#define B_   4
#define L_   512
#define D_   768
#define K_   10
#define P_   50
#define R_   1586          // 2*D + P
#define NP_  10642         // number of window pairs
#define MROWS 2048         // B_*L_
#define NPAD 1664          // 13*128, padded N for MFMA tiles

// out layout: pred [B,n] | emo_cau_pos [n,2] | h [B,n,R]  (all as float)
#define PRED_OFF 0
#define POS_OFF  (B_ * NP_)
#define H_OFF    (B_ * NP_ + NP_ * 2)

typedef __attribute__((ext_vector_type(8))) short short8;    // 8 bf16, 4 VGPRs (MFMA A/B frag)
typedef __attribute__((ext_vector_type(4))) float floatx4;   // MFMA C/D frag

__device__ __forceinline__ unsigned short f2bf(float f) {
    union { float f; unsigned int u; } a; a.f = f;
    unsigned int u = a.u;
    return (unsigned short)((u + 0x7FFF + ((u >> 16) & 1)) >> 16);  // RNE
}

// ---- closed-form pair indexing: pairs ordered (ei outer asc, ci inner asc) ----
__device__ __forceinline__ int pair_offset(int i) {
    int h = i < K_ ? i : K_;
    int off = h * (K_ + 1) + (h * (h - 1)) / 2;
    if (i > K_) {
        int fullEnd = i < (L_ - K_) ? i : (L_ - K_);
        off += (fullEnd - K_) * (2 * K_ + 1);
        if (i > L_ - K_) {
            int t = i - (L_ - K_);
            int first = 2 * K_;
            int last = L_ + K_ - (i - 1);
            off += (first + last) * t / 2;
        }
    }
    return off;
}

// ---- convert doc -> bf16 row-major [2048][768] ----
__global__ __launch_bounds__(256) void convert_A(
        const float* __restrict__ doc, unsigned short* __restrict__ At) {
    int idx = (blockIdx.x * 256 + threadIdx.x) * 4;
    float4 v = *(const float4*)(doc + idx);
    ushort4 o;
    o.x = f2bf(v.x); o.y = f2bf(v.y); o.z = f2bf(v.z); o.w = f2bf(v.w);
    *(ushort4*)(At + idx) = o;
}

// ---- transpose+convert W1 rows [z*768, z*768+768) -> Wt[z][n][k] bf16, n padded to 1664 ----
__global__ __launch_bounds__(256) void convert_W(
        const float* __restrict__ W1, unsigned short* __restrict__ Wt) {
    int z = blockIdx.z;
    int k0 = blockIdx.x * 32;
    int n0 = blockIdx.y * 32;
    __shared__ float tile[32][33];
    int tx = threadIdx.x & 31, ty = threadIdx.x >> 5;
    #pragma unroll
    for (int r = 0; r < 4; ++r) {
        int k = k0 + ty + r * 8;
        int n = n0 + tx;
        tile[ty + r * 8][tx] = (n < R_) ? W1[(size_t)(z * D_ + k) * R_ + n] : 0.f;
    }
    __syncthreads();
    #pragma unroll
    for (int r = 0; r < 4; ++r) {
        int n = n0 + ty + r * 8;
        int k = k0 + tx;
        Wt[(size_t)z * NPAD * D_ + (size_t)n * D_ + k] = f2bf(tile[tx][ty + r * 8]);
    }
}

// ---- F[21][R] = E @ W1[1536:1586,:] + b1 (fp32, tiny) ----
__global__ __launch_bounds__(256) void build_F(
        const float* __restrict__ pos_emb, const float* __restrict__ W1,
        const float* __restrict__ b1, float* __restrict__ F) {
    int s = blockIdx.x;
    __shared__ float Es[P_];
    if (threadIdx.x < P_) {
        float acc = 0.f;
        #pragma unroll
        for (int r = 0; r <= 2 * K_; ++r) {
            float cnt = (float)(L_ - (r > K_ ? r - K_ : K_ - r));
            float d = (float)(s - r);
            acc += cnt * expf(-d * d) * pos_emb[r * P_ + threadIdx.x];
        }
        Es[threadIdx.x] = acc;
    }
    __syncthreads();
    for (int j = threadIdx.x; j < R_; j += blockDim.x) {
        float acc = b1[j];
        #pragma unroll 10
        for (int p = 0; p < P_; ++p)
            acc += Es[p] * W1[(2 * D_ + p) * R_ + j];
        F[s * R_ + j] = acc;
    }
}

// ---- MFMA GEMM: C[z] = At(2048x768,bf16) @ Wt[z]^T -> fp32 [2048][1586]
#define GLOAD_LDS16(g, l) __builtin_amdgcn_global_load_lds( \
    (const __attribute__((address_space(1))) void*)(g), \
    (__attribute__((address_space(3))) void*)(l), 16, 0, 0)

__global__ __launch_bounds__(256) void gemm_mfma(
        const unsigned short* __restrict__ At,   // [2048][768] bf16
        const unsigned short* __restrict__ Wt,   // [2][1664][768] bf16 (B^T)
        float* __restrict__ U, float* __restrict__ V) {
    __shared__ unsigned short Alds[128 * 32];
    __shared__ unsigned short Blds[128 * 32];
    const int tileN = blockIdx.x * 128;
    const int tileM = blockIdx.y * 128;
    const unsigned short* Bt = Wt + (size_t)blockIdx.z * NPAD * D_;
    float* C = blockIdx.z ? V : U;

    const int lane = threadIdx.x & 63;
    const int w = threadIdx.x >> 6;
    const int wm = (w & 1) * 64, wn = (w >> 1) * 64;
    const int quad = lane >> 4, l16 = lane & 15;

    floatx4 acc[4][4] = {};

    for (int k0 = 0; k0 < D_; k0 += 32) {
        #pragma unroll
        for (int t = 0; t < 2; ++t) {
            int g = (t * 4 + w) * 64 + lane;
            int m = g >> 2, c = g & 3;
            GLOAD_LDS16(At + (size_t)(tileM + m) * D_ + k0 + c * 8,
                        Alds + (t * 4 + w) * 512);
            GLOAD_LDS16(Bt + (size_t)(tileN + m) * D_ + k0 + c * 8,
                        Blds + (t * 4 + w) * 512);
        }
        __syncthreads();
        short8 a[4], b[4];
        #pragma unroll
        for (int im = 0; im < 4; ++im)
            a[im] = *(const short8*)&Alds[(wm + im * 16 + l16) * 32 + quad * 8];
        #pragma unroll
        for (int in = 0; in < 4; ++in)
            b[in] = *(const short8*)&Blds[(wn + in * 16 + l16) * 32 + quad * 8];
        #pragma unroll
        for (int im = 0; im < 4; ++im)
            #pragma unroll
            for (int in = 0; in < 4; ++in)
                acc[im][in] = __builtin_amdgcn_mfma_f32_16x16x32_bf16(
                    a[im], b[in], acc[im][in], 0, 0, 0);
        __syncthreads();
    }
    #pragma unroll
    for (int im = 0; im < 4; ++im) {
        #pragma unroll
        for (int in = 0; in < 4; ++in) {
            int col = tileN + wn + in * 16 + l16;
            if (col < R_) {
                #pragma unroll
                for (int r = 0; r < 4; ++r) {
                    int row = tileM + wm + im * 16 + quad * 4 + r;
                    C[(size_t)row * R_ + col] = acc[im][in][r];
                }
            }
        }
    }
}

// ---- epilogue: one WAVE per (b, i). U row + W2 preloaded into registers once;
// loop 21 dj streaming V/F rows. h = relu(u+v+f); pred = h.W2 + b2.
#define NC2 13   // ceil(793/64)
__global__ __launch_bounds__(256) void epilogue(
        const float* __restrict__ U, const float* __restrict__ V,
        const float* __restrict__ F, const float* __restrict__ W2,
        const float* __restrict__ b2, float* __restrict__ out) {
    const int w    = threadIdx.x >> 6;
    const int lane = threadIdx.x & 63;
    const int i    = blockIdx.x * 4 + w;      // 0..511
    const int b    = blockIdx.y;

    const float2* u2  = (const float2*)(U + (size_t)(b * L_ + i) * R_);
    const float2* w2v = (const float2*)W2;

    float2 ur[NC2], wr[NC2];
    #pragma unroll
    for (int t = 0; t < NC2; ++t) {
        int c = lane + t * 64;
        if (c < R_ / 2) { ur[t] = u2[c]; wr[t] = w2v[c]; }
    }

    const int base = i - K_ > 0 ? i - K_ : 0;
    const int poff = pair_offset(i);
    const float bias = b2[0];

    for (int dj = 0; dj < 21; ++dj) {
        int j = i - K_ + dj;
        if (j < 0 || j >= L_) continue;
        int p = poff + (j - base);
        const float2* v2 = (const float2*)(V + (size_t)(b * L_ + j) * R_);
        const float2* f2 = (const float2*)(F + (size_t)dj * R_);
        float2* h2 = (float2*)(out + H_OFF + (size_t)(b * NP_ + p) * R_);

        float acc = 0.f;
        #pragma unroll
        for (int t = 0; t < NC2; ++t) {
            int c = lane + t * 64;
            if (c < R_ / 2) {
                float2 vv = v2[c], ff = f2[c];
                float h0 = fmaxf(ur[t].x + vv.x + ff.x, 0.f);
                float h1 = fmaxf(ur[t].y + vv.y + ff.y, 0.f);
                h2[c] = make_float2(h0, h1);
                acc += h0 * wr[t].x + h1 * wr[t].y;
            }
        }
        #pragma unroll
        for (int off = 32; off; off >>= 1) acc += __shfl_down(acc, off, 64);
        if (lane == 0) {
            out[PRED_OFF + b * NP_ + p] = acc + bias;
            if (b == 0) {
                out[POS_OFF + p * 2 + 0] = (float)(i + 1);
                out[POS_OFF + p * 2 + 1] = (float)(j + 1);
            }
        }
    }
}

extern "C" void kernel_launch(void* const* d_in, const int* in_sizes, int n_in,
                              void* d_out, int out_size, void* d_ws, size_t ws_size,
                              hipStream_t stream) {
    const float* doc     = (const float*)d_in[0];
    const float* pos_emb = (const float*)d_in[1];
    const float* W1      = (const float*)d_in[2];
    const float* b1      = (const float*)d_in[3];
    const float* W2      = (const float*)d_in[4];
    const float* b2      = (const float*)d_in[5];
    float* out = (float*)d_out;

    char* ws = (char*)d_ws;
    float* U = (float*)ws;
    float* V = U + (size_t)MROWS * R_;
    float* F = V + (size_t)MROWS * R_;
    size_t off = ((size_t)MROWS * R_ * 2 + (size_t)21 * R_) * 4;
    off = (off + 255) & ~(size_t)255;
    unsigned short* At = (unsigned short*)(ws + off);
    off += (size_t)MROWS * D_ * 2;
    off = (off + 255) & ~(size_t)255;
    unsigned short* Wt = (unsigned short*)(ws + off);

    convert_A<<<MROWS * D_ / 1024, 256, 0, stream>>>(doc, At);
    convert_W<<<dim3(D_ / 32, NPAD / 32, 2), 256, 0, stream>>>(W1, Wt);
    build_F<<<21, 256, 0, stream>>>(pos_emb, W1, b1, F);
    gemm_mfma<<<dim3(NPAD / 128, MROWS / 128, 2), 256, 0, stream>>>(At, Wt, U, V);
    epilogue<<<dim3(L_ / 4, B_), 256, 0, stream>>>(U, V, F, W2, b2, out);
}

// Round 4
// 370.432 us; speedup vs baseline: 1.5101x; 1.0042x over previous
//
#include <hip/hip_runtime.h>
#include <math.h>

// Problem constants (fixed by setup_inputs)
#define B_   4
#define L_   512
#define D_   768
#define K_   10
#define P_   50
#define R_   1586          // 2*D + P
#define NP_  10642         // number of window pairs
#define MROWS 2048         // B_*L_
#define NPAD 1664          // 13*128, padded N for MFMA tiles
#define UVS  1600          // bf16 row stride for U/V/F (3200 B, 16B-aligned)

// out layout: pred [B,n] | emo_cau_pos [n,2] | h [B,n,R]  (all as float)
#define PRED_OFF 0
#define POS_OFF  (B_ * NP_)
#define H_OFF    (B_ * NP_ + NP_ * 2)

typedef __attribute__((ext_vector_type(8))) short short8;    // 8 bf16 (MFMA A/B frag)
typedef __attribute__((ext_vector_type(4))) float floatx4;   // MFMA C/D frag

__device__ __forceinline__ unsigned short f2bf(float f) {
    union { float f; unsigned int u; } a; a.f = f;
    unsigned int u = a.u;
    return (unsigned short)((u + 0x7FFF + ((u >> 16) & 1)) >> 16);  // RNE
}
__device__ __forceinline__ float bf2f(unsigned short u) {
    union { unsigned int u; float f; } a; a.u = ((unsigned int)u) << 16;
    return a.f;
}

// ---- closed-form pair indexing ----
__device__ __forceinline__ int pair_offset(int i) {
    int h = i < K_ ? i : K_;
    int off = h * (K_ + 1) + (h * (h - 1)) / 2;
    if (i > K_) {
        int fullEnd = i < (L_ - K_) ? i : (L_ - K_);
        off += (fullEnd - K_) * (2 * K_ + 1);
        if (i > L_ - K_) {
            int t = i - (L_ - K_);
            int first = 2 * K_;
            int last = L_ + K_ - (i - 1);
            off += (first + last) * t / 2;
        }
    }
    return off;
}

// ---- convert doc -> bf16 row-major [2048][768] ----
__global__ __launch_bounds__(256) void convert_A(
        const float* __restrict__ doc, unsigned short* __restrict__ At) {
    int idx = (blockIdx.x * 256 + threadIdx.x) * 4;
    float4 v = *(const float4*)(doc + idx);
    ushort4 o;
    o.x = f2bf(v.x); o.y = f2bf(v.y); o.z = f2bf(v.z); o.w = f2bf(v.w);
    *(ushort4*)(At + idx) = o;
}

// ---- transpose+convert W1 -> Wt[z][n][k] bf16, n padded to 1664 ----
__global__ __launch_bounds__(256) void convert_W(
        const float* __restrict__ W1, unsigned short* __restrict__ Wt) {
    int z = blockIdx.z;
    int k0 = blockIdx.x * 32;
    int n0 = blockIdx.y * 32;
    __shared__ float tile[32][33];
    int tx = threadIdx.x & 31, ty = threadIdx.x >> 5;
    #pragma unroll
    for (int r = 0; r < 4; ++r) {
        int k = k0 + ty + r * 8;
        int n = n0 + tx;
        tile[ty + r * 8][tx] = (n < R_) ? W1[(size_t)(z * D_ + k) * R_ + n] : 0.f;
    }
    __syncthreads();
    #pragma unroll
    for (int r = 0; r < 4; ++r) {
        int n = n0 + ty + r * 8;
        int k = k0 + tx;
        Wt[(size_t)z * NPAD * D_ + (size_t)n * D_ + k] = f2bf(tile[tx][ty + r * 8]);
    }
}

// ---- F[21][UVS] bf16 = E @ W1[1536:1586,:] + b1 ----
__global__ __launch_bounds__(256) void build_F(
        const float* __restrict__ pos_emb, const float* __restrict__ W1,
        const float* __restrict__ b1, unsigned short* __restrict__ Fb) {
    int s = blockIdx.x;
    __shared__ float Es[P_];
    if (threadIdx.x < P_) {
        float acc = 0.f;
        #pragma unroll
        for (int r = 0; r <= 2 * K_; ++r) {
            float cnt = (float)(L_ - (r > K_ ? r - K_ : K_ - r));
            float d = (float)(s - r);
            acc += cnt * expf(-d * d) * pos_emb[r * P_ + threadIdx.x];
        }
        Es[threadIdx.x] = acc;
    }
    __syncthreads();
    for (int j = threadIdx.x; j < R_; j += blockDim.x) {
        float acc = b1[j];
        #pragma unroll 10
        for (int p = 0; p < P_; ++p)
            acc += Es[p] * W1[(2 * D_ + p) * R_ + j];
        Fb[s * UVS + j] = f2bf(acc);
    }
}

// ---- MFMA GEMM: C[z] = At(2048x768,bf16) @ Wt[z]^T -> bf16 [2048][UVS]
#define GLOAD_LDS16(g, l) __builtin_amdgcn_global_load_lds( \
    (const __attribute__((address_space(1))) void*)(g), \
    (__attribute__((address_space(3))) void*)(l), 16, 0, 0)

__global__ __launch_bounds__(256) void gemm_mfma(
        const unsigned short* __restrict__ At,   // [2048][768] bf16
        const unsigned short* __restrict__ Wt,   // [2][1664][768] bf16 (B^T)
        unsigned short* __restrict__ U, unsigned short* __restrict__ V) {
    __shared__ unsigned short Alds[128 * 32];
    __shared__ unsigned short Blds[128 * 32];
    const int tileN = blockIdx.x * 128;
    const int tileM = blockIdx.y * 128;
    const unsigned short* Bt = Wt + (size_t)blockIdx.z * NPAD * D_;
    unsigned short* C = blockIdx.z ? V : U;

    const int lane = threadIdx.x & 63;
    const int w = threadIdx.x >> 6;
    const int wm = (w & 1) * 64, wn = (w >> 1) * 64;
    const int quad = lane >> 4, l16 = lane & 15;

    floatx4 acc[4][4] = {};

    for (int k0 = 0; k0 < D_; k0 += 32) {
        #pragma unroll
        for (int t = 0; t < 2; ++t) {
            int g = (t * 4 + w) * 64 + lane;
            int m = g >> 2, c = g & 3;
            GLOAD_LDS16(At + (size_t)(tileM + m) * D_ + k0 + c * 8,
                        Alds + (t * 4 + w) * 512);
            GLOAD_LDS16(Bt + (size_t)(tileN + m) * D_ + k0 + c * 8,
                        Blds + (t * 4 + w) * 512);
        }
        __syncthreads();
        short8 a[4], b[4];
        #pragma unroll
        for (int im = 0; im < 4; ++im)
            a[im] = *(const short8*)&Alds[(wm + im * 16 + l16) * 32 + quad * 8];
        #pragma unroll
        for (int in = 0; in < 4; ++in)
            b[in] = *(const short8*)&Blds[(wn + in * 16 + l16) * 32 + quad * 8];
        #pragma unroll
        for (int im = 0; im < 4; ++im)
            #pragma unroll
            for (int in = 0; in < 4; ++in)
                acc[im][in] = __builtin_amdgcn_mfma_f32_16x16x32_bf16(
                    a[im], b[in], acc[im][in], 0, 0, 0);
        __syncthreads();
    }
    #pragma unroll
    for (int im = 0; im < 4; ++im) {
        #pragma unroll
        for (int in = 0; in < 4; ++in) {
            int col = tileN + wn + in * 16 + l16;
            if (col < R_) {
                #pragma unroll
                for (int r = 0; r < 4; ++r) {
                    int row = tileM + wm + im * 16 + quad * 4 + r;
                    C[(size_t)row * UVS + col] = f2bf(acc[im][in][r]);
                }
            }
        }
    }
}

// ---- epilogue: one WAVE per (b, i, dj-half). U row + W2 in registers;
// stream bf16 V/F rows; h = relu(u+v+f) nt-stored; pred = h.W2 + b2.
#define NC2 13   // ceil(793/64) float2-chunks per row
__global__ __launch_bounds__(256) void epilogue(
        const unsigned short* __restrict__ U, const unsigned short* __restrict__ V,
        const unsigned short* __restrict__ Fb, const float* __restrict__ W2,
        const float* __restrict__ b2, float* __restrict__ out) {
    const int w    = threadIdx.x >> 6;
    const int lane = threadIdx.x & 63;
    const int i    = blockIdx.x * 4 + w;      // 0..511
    const int b    = blockIdx.y;
    const int half = blockIdx.z;              // 0: dj 0..10, 1: dj 11..20

    const ushort2* u2  = (const ushort2*)(U + (size_t)(b * L_ + i) * UVS);
    const float2*  w2v = (const float2*)W2;

    float2 ur[NC2], wr[NC2];
    #pragma unroll
    for (int t = 0; t < NC2; ++t) {
        int c = lane + t * 64;
        if (c < R_ / 2) {
            ushort2 uu = u2[c];
            ur[t] = make_float2(bf2f(uu.x), bf2f(uu.y));
            wr[t] = w2v[c];
        }
    }

    const int base = i - K_ > 0 ? i - K_ : 0;
    const int poff = pair_offset(i);
    const float bias = b2[0];
    const int dj0 = half ? 11 : 0;
    const int dj1 = half ? 21 : 11;

    for (int dj = dj0; dj < dj1; ++dj) {
        int j = i - K_ + dj;
        if (j < 0 || j >= L_) continue;
        int p = poff + (j - base);
        const ushort2* v2 = (const ushort2*)(V + (size_t)(b * L_ + j) * UVS);
        const ushort2* f2 = (const ushort2*)(Fb + (size_t)dj * UVS);
        double* h2 = (double*)(out + H_OFF + (size_t)(b * NP_ + p) * R_);

        float acc = 0.f;
        #pragma unroll
        for (int t = 0; t < NC2; ++t) {
            int c = lane + t * 64;
            if (c < R_ / 2) {
                ushort2 vv = v2[c], ff = f2[c];
                float h0 = fmaxf(ur[t].x + bf2f(vv.x) + bf2f(ff.x), 0.f);
                float h1 = fmaxf(ur[t].y + bf2f(vv.y) + bf2f(ff.y), 0.f);
                union { float2 f; double d; } pk;
                pk.f = make_float2(h0, h1);
                __builtin_nontemporal_store(pk.d, h2 + c);
                acc += h0 * wr[t].x + h1 * wr[t].y;
            }
        }
        #pragma unroll
        for (int off = 32; off; off >>= 1) acc += __shfl_down(acc, off, 64);
        if (lane == 0) {
            out[PRED_OFF + b * NP_ + p] = acc + bias;
            if (b == 0) {
                out[POS_OFF + p * 2 + 0] = (float)(i + 1);
                out[POS_OFF + p * 2 + 1] = (float)(j + 1);
            }
        }
    }
}

extern "C" void kernel_launch(void* const* d_in, const int* in_sizes, int n_in,
                              void* d_out, int out_size, void* d_ws, size_t ws_size,
                              hipStream_t stream) {
    const float* doc     = (const float*)d_in[0];
    const float* pos_emb = (const float*)d_in[1];
    const float* W1      = (const float*)d_in[2];
    const float* b1      = (const float*)d_in[3];
    const float* W2      = (const float*)d_in[4];
    const float* b2      = (const float*)d_in[5];
    float* out = (float*)d_out;

    char* ws = (char*)d_ws;
    size_t off = 0;
    unsigned short* U  = (unsigned short*)(ws + off); off += (size_t)MROWS * UVS * 2;
    unsigned short* V  = (unsigned short*)(ws + off); off += (size_t)MROWS * UVS * 2;
    unsigned short* Fb = (unsigned short*)(ws + off); off += (size_t)21 * UVS * 2;
    off = (off + 255) & ~(size_t)255;
    unsigned short* At = (unsigned short*)(ws + off); off += (size_t)MROWS * D_ * 2;
    off = (off + 255) & ~(size_t)255;
    unsigned short* Wt = (unsigned short*)(ws + off);

    convert_A<<<MROWS * D_ / 1024, 256, 0, stream>>>(doc, At);
    convert_W<<<dim3(D_ / 32, NPAD / 32, 2), 256, 0, stream>>>(W1, Wt);
    build_F<<<21, 256, 0, stream>>>(pos_emb, W1, b1, Fb);
    gemm_mfma<<<dim3(NPAD / 128, MROWS / 128, 2), 256, 0, stream>>>(At, Wt, U, V);
    epilogue<<<dim3(L_ / 4, B_, 2), 256, 0, stream>>>(U, V, Fb, W2, b2, out);
}